// Round 11
// baseline (840.461 us; speedup 1.0000x reference)
//
#include <hip/hip_runtime.h>
#include <hip/hip_bf16.h>

// MoE: N=8192 tokens, D=1024, H=4096, E=8 experts, top-k=2.
// Grouped GEMMs: 256x256, BK=64, 8 waves (2M x 4N), quarter-slot LDS
// double buffer (128 KB), 4 phases/K-tile with COUNTED vmcnt (never 0 in
// steady loop; wait BEFORE barrier so all waves' deposits are proven).
// gemm2: atomic-free partials + combine.

#define NTOK 8192
#define DDIM 1024
#define HDIM 4096
#define NEXP 8
#define NASSIGN (NTOK * 2)
#define MAX_MT 72               // max ceil-sum of per-expert 256-row tiles (71)
#define GRID1 (16 * MAX_MT)     // 1152, divisible by 8
#define GRID2A (4 * 2 * MAX_MT) // 576  (K-split x2, no atomics)
#define GRID2B (4 * MAX_MT)     // 288  (atomic fallback)

typedef __bf16 bf16_t;
typedef __bf16 bf16x2 __attribute__((ext_vector_type(2)));
typedef __bf16 bf16x4 __attribute__((ext_vector_type(4)));
typedef __bf16 bf16x8 __attribute__((ext_vector_type(8)));
typedef float f32x4 __attribute__((ext_vector_type(4)));

#define GLOAD16(gptr, lptr)                                                    \
  __builtin_amdgcn_global_load_lds(                                            \
      (const __attribute__((address_space(1))) void*)(gptr),                   \
      (__attribute__((address_space(3))) void*)(lptr), 16, 0, 0)

#define VMCNT(n) asm volatile("s_waitcnt vmcnt(" #n ")" ::: "memory")
#define BAR                                                                    \
  __builtin_amdgcn_s_barrier();                                                \
  __builtin_amdgcn_sched_barrier(0);

#define MFMA16(a, b, c) __builtin_amdgcn_mfma_f32_16x16x32_bf16(a, b, c, 0, 0, 0)

// bijective XCD swizzle: launched id -> logical job; nwg % 8 == 0
__device__ __forceinline__ int xcd_swz(int orig, int nwg) {
  const int cpx = nwg >> 3;
  return (orig & 7) * cpx + (orig >> 3);
}

// ---------------- weight transpose: [E][R][C] f32 -> [E][C][R] bf16 --------
__global__ void __launch_bounds__(256) transpose_cvt_kernel(
    const float* __restrict__ in, bf16_t* __restrict__ out, int R, int C) {
  __shared__ float tile[64][33];
  const size_t mat = (size_t)R * C;
  const float* ip = in + (size_t)blockIdx.z * mat;
  bf16_t* op = out + (size_t)blockIdx.z * mat;
  const int c0 = blockIdx.x * 32, r0 = blockIdx.y * 64;
  const int tx = threadIdx.x, ty = threadIdx.y;  // (32, 8)
#pragma unroll
  for (int i = 0; i < 8; ++i) {
    const int r = ty + 8 * i;
    tile[r][tx] = ip[(size_t)(r0 + r) * C + (c0 + tx)];
  }
  __syncthreads();
#pragma unroll
  for (int j = 0; j < 4; ++j) {
    const int c = ty + 8 * j;
    bf16x2 v;
    v[0] = (bf16_t)tile[2 * tx][c];
    v[1] = (bf16_t)tile[2 * tx + 1][c];
    *(bf16x2*)(op + (size_t)(c0 + c) * R + r0 + 2 * tx) = v;
  }
}

// ---------------- router (fused x -> bf16; wave-shuffle reduce) ------------
__global__ void __launch_bounds__(256) router_kernel(
    const float* __restrict__ x, const float* __restrict__ Wr,
    const float* __restrict__ br, int2* __restrict__ ids,
    float2* __restrict__ prs, int* __restrict__ counts,
    bf16_t* __restrict__ xb) {
  const int n = blockIdx.x;
  const int t = threadIdx.x;
  const int wave = t >> 6, lane = t & 63;
  const float4 xv = ((const float4*)(x + (size_t)n * DDIM))[t];
  bf16x4 o;
  o[0] = (bf16_t)xv.x; o[1] = (bf16_t)xv.y;
  o[2] = (bf16_t)xv.z; o[3] = (bf16_t)xv.w;
  ((bf16x4*)(xb + (size_t)n * DDIM))[t] = o;

  float acc[NEXP];
#pragma unroll
  for (int e = 0; e < NEXP; ++e) acc[e] = 0.f;
  const float xq[4] = {xv.x, xv.y, xv.z, xv.w};
#pragma unroll
  for (int q = 0; q < 4; ++q) {
    const float* w = Wr + (size_t)(4 * t + q) * NEXP;
#pragma unroll
    for (int e = 0; e < NEXP; ++e) acc[e] += xq[q] * w[e];
  }
#pragma unroll
  for (int off = 32; off >= 1; off >>= 1)
#pragma unroll
    for (int e = 0; e < NEXP; ++e) acc[e] += __shfl_down(acc[e], off);
  __shared__ float red[4][NEXP];
  if (lane == 0)
#pragma unroll
    for (int e = 0; e < NEXP; ++e) red[wave][e] = acc[e];
  __syncthreads();
  if (t == 0) {
    float l[NEXP];
#pragma unroll
    for (int e = 0; e < NEXP; ++e)
      l[e] = ((red[0][e] + red[1][e]) + (red[2][e] + red[3][e])) + br[e];
    int i1 = 0; float v1 = l[0];
    for (int e = 1; e < NEXP; ++e)
      if (l[e] > v1) { v1 = l[e]; i1 = e; }
    int i2 = (i1 == 0) ? 1 : 0; float v2 = l[i2];
    for (int e = 0; e < NEXP; ++e)
      if (e != i1 && l[e] > v2) { v2 = l[e]; i2 = e; }
    float denom = 0.f;
    for (int e = 0; e < NEXP; ++e) denom += expf(l[e] - v1);
    ids[n] = make_int2(i1, i2);
    prs[n] = make_float2(1.f / denom, expf(v2 - v1) / denom);
    atomicAdd(&counts[i1], 1);
    atomicAdd(&counts[i2], 1);
  }
}

// scan (thread 0, 256-row tiles) + aux loss
__global__ void __launch_bounds__(256) scan_aux_kernel(
    const int* __restrict__ counts, int* __restrict__ offsets,
    int* __restrict__ tmap, const int2* __restrict__ ids,
    const float2* __restrict__ prs, float* __restrict__ aux_out) {
  const int t = threadIdx.x;
  if (t == 0) {
    int off = 0, nt = 0;
    for (int e = 0; e < NEXP; ++e) {
      offsets[e] = off;
      const int c = counts[e];
      for (int m0 = 0; m0 < c; m0 += 256) {
        tmap[nt] = e;
        tmap[MAX_MT + nt] = m0;
        ++nt;
      }
      off += c;
    }
    offsets[NEXP] = off;
    tmap[2 * MAX_MT] = nt;
  }
  float imp[NEXP];
#pragma unroll
  for (int e = 0; e < NEXP; ++e) imp[e] = 0.f;
  for (int n = t; n < NTOK; n += 256) {
    const int2 id = ids[n];
    const float2 pr = prs[n];
#pragma unroll
    for (int e = 0; e < NEXP; ++e)
      imp[e] += (id.x == e ? pr.x : 0.f) + (id.y == e ? pr.y : 0.f);
  }
  __shared__ float red[256][NEXP];
#pragma unroll
  for (int e = 0; e < NEXP; ++e) red[t][e] = imp[e];
  __syncthreads();
  for (int s = 128; s >= 1; s >>= 1) {
    if (t < s) {
#pragma unroll
      for (int e = 0; e < NEXP; ++e) red[t][e] += red[t + s][e];
    }
    __syncthreads();
  }
  if (t == 0) {
    float m = 0.f;
    for (int e = 0; e < NEXP; ++e) m += red[0][e];
    m *= (1.f / NEXP);
    float v = 0.f;
    for (int e = 0; e < NEXP; ++e) {
      const float d = red[0][e] - m;
      v += d * d;
    }
    v *= (1.f / (NEXP - 1));  // ddof=1
    aux_out[0] = v / (m * m + 1e-9f);
  }
}

// scatter: bucket tokens; also record token -> (assign1, assign2)
__global__ void __launch_bounds__(256) scatter_kernel(
    const int2* __restrict__ ids, const float2* __restrict__ prs,
    const int* __restrict__ offsets, int* __restrict__ cursor,
    int* __restrict__ btok, float* __restrict__ bprob,
    int2* __restrict__ amap) {
  const int n = blockIdx.x * 256 + threadIdx.x;
  if (n >= NTOK) return;
  const int2 id = ids[n];
  const float2 pr = prs[n];
  int p = atomicAdd(&cursor[id.x], 1);
  const int a1 = offsets[id.x] + p;
  btok[a1] = n;
  bprob[a1] = pr.x;
  p = atomicAdd(&cursor[id.y], 1);
  const int a2 = offsets[id.y] + p;
  btok[a2] = n;
  bprob[a2] = pr.y;
  amap[n] = make_int2(a1, a2);
}

// combine: out[n] = p1*(o0+o1)[a1] + p2*(o0+o1)[a2]  (bias already in o0)
__global__ void __launch_bounds__(256) combine_kernel(
    const float* __restrict__ o0, const float* __restrict__ o1,
    const int2* __restrict__ amap, const float* __restrict__ bprob,
    float* __restrict__ out) {
  const int n = blockIdx.x;
  const int d = threadIdx.x * 4;
  const int2 a = amap[n];
  const float p1 = bprob[a.x], p2 = bprob[a.y];
  const float4 u0 = *(const float4*)(o0 + (size_t)a.x * DDIM + d);
  const float4 u1 = *(const float4*)(o1 + (size_t)a.x * DDIM + d);
  const float4 v0 = *(const float4*)(o0 + (size_t)a.y * DDIM + d);
  const float4 v1 = *(const float4*)(o1 + (size_t)a.y * DDIM + d);
  float4 r;
  r.x = p1 * (u0.x + u1.x) + p2 * (v0.x + v1.x);
  r.y = p1 * (u0.y + u1.y) + p2 * (v0.y + v1.y);
  r.z = p1 * (u0.z + u1.z) + p2 * (v0.z + v1.z);
  r.w = p1 * (u0.w + u1.w) + p2 * (v0.w + v1.w);
  *(float4*)(out + (size_t)n * DDIM + d) = r;
}

// ---------------- GEMM core machinery ---------------------------------------
// LDS slots (8 KB each, holding 64 rows x 64 k bf16, XOR-8 swizzled):
//   A: slot(buf, mh, q) = buf*4 + mh*2 + q     (mh = M-half, q = row-quarter)
//   B: slot(buf, nq)    = buf*4 + nq           (nq = 64-col quarter)
// Deposit: thread tid writes its 16B at slot_base + tid*16 (gload_lds linear);
// source k-slot l = (tid&7) ^ ((tid>>3)&7)  (both-sides swizzle, rule #21).
// Read (lane): off_f = (f*16+lrow)*128 + ((lslot ^ (lrow&7))<<4); ks1 = ^64.

#define ISSUE_A_Q0(NB, KO)                                                     \
  GLOAD16(aS00 + (KO), (char*)Al + ((NB)*4 + 0) * 8192 + wave * 1024);         \
  GLOAD16(aS10 + (KO), (char*)Al + ((NB)*4 + 2) * 8192 + wave * 1024);
#define ISSUE_A_Q1(NB, KO)                                                     \
  GLOAD16(aS01 + (KO), (char*)Al + ((NB)*4 + 1) * 8192 + wave * 1024);         \
  GLOAD16(aS11 + (KO), (char*)Al + ((NB)*4 + 3) * 8192 + wave * 1024);
#define ISSUE_B_01(NB, KO)                                                     \
  GLOAD16(bS0 + (KO), (char*)Bl + ((NB)*4 + 0) * 8192 + wave * 1024);          \
  GLOAD16(bS1 + (KO), (char*)Bl + ((NB)*4 + 1) * 8192 + wave * 1024);
#define ISSUE_B_23(NB, KO)                                                     \
  GLOAD16(bS2 + (KO), (char*)Bl + ((NB)*4 + 2) * 8192 + wave * 1024);          \
  GLOAD16(bS3 + (KO), (char*)Bl + ((NB)*4 + 3) * 8192 + wave * 1024);

#define READ_FA(QOFF, KX)                                                      \
  fa0 = *(const bf16x8*)(Ac + (QOFF) + (off0 ^ (KX)));                         \
  fa1 = *(const bf16x8*)(Ac + (QOFF) + (off1 ^ (KX)));                         \
  fa2 = *(const bf16x8*)(Ac + (QOFF) + (off2 ^ (KX)));                         \
  fa3 = *(const bf16x8*)(Ac + (QOFF) + (off3 ^ (KX)));
#define READ_G0                                                                \
  g00 = *(const bf16x8*)(Bc + off0);                                           \
  g01 = *(const bf16x8*)(Bc + off1);                                           \
  g02 = *(const bf16x8*)(Bc + off2);                                           \
  g03 = *(const bf16x8*)(Bc + off3);
#define READ_G1                                                                \
  g10 = *(const bf16x8*)(Bc + (off0 ^ 64));                                    \
  g11 = *(const bf16x8*)(Bc + (off1 ^ 64));                                    \
  g12 = *(const bf16x8*)(Bc + (off2 ^ 64));                                    \
  g13 = *(const bf16x8*)(Bc + (off3 ^ 64));

#define MROW(M, A, G0, G1, G2, G3)                                             \
  acc[M][0] = MFMA16(A, G0, acc[M][0]);                                        \
  acc[M][1] = MFMA16(A, G1, acc[M][1]);                                        \
  acc[M][2] = MFMA16(A, G2, acc[M][2]);                                        \
  acc[M][3] = MFMA16(A, G3, acc[M][3]);
#define MFMA_BLK0(MB)                                                          \
  __builtin_amdgcn_s_setprio(1);                                               \
  MROW(MB + 0, fa0, g00, g01, g02, g03)                                        \
  MROW(MB + 1, fa1, g00, g01, g02, g03)                                        \
  MROW(MB + 2, fa2, g00, g01, g02, g03)                                        \
  MROW(MB + 3, fa3, g00, g01, g02, g03)                                        \
  __builtin_amdgcn_s_setprio(0);
#define MFMA_BLK1(MB)                                                          \
  __builtin_amdgcn_s_setprio(1);                                               \
  MROW(MB + 0, fa0, g10, g11, g12, g13)                                        \
  MROW(MB + 1, fa1, g10, g11, g12, g13)                                        \
  MROW(MB + 2, fa2, g10, g11, g12, g13)                                        \
  MROW(MB + 3, fa3, g10, g11, g12, g13)                                        \
  __builtin_amdgcn_s_setprio(0);

// K-loop: NT K-tiles of 64. Steady loop issues tile t+1 while computing t;
// counted waits: vmcnt(4) @ ph1-end (proves A(t,q1)), vmcnt(2) @ ph3-end
// (proves A(t+1,q0)+B(t+1)); never 0 until the peeled final tile.
#define KLOOP(NT)                                                              \
  ISSUE_A_Q0(0, 0) ISSUE_B_01(0, 0) ISSUE_B_23(0, 0) ISSUE_A_Q1(0, 0)          \
  VMCNT(2);                                                                    \
  BAR                                                                          \
  _Pragma("unroll 1") for (int t = 0; t < (NT)-1; ++t) {                       \
    const int cb = t & 1, nb = cb ^ 1;                                         \
    const int ko = (t + 1) * 64;                                               \
    const char* Ac = (const char*)Al + cb * 32768 + mh * 16384;                \
    const char* Bc = (const char*)Bl + cb * 32768 + nq * 8192;                 \
    bf16x8 fa0, fa1, fa2, fa3;                                                 \
    bf16x8 g00, g01, g02, g03, g10, g11, g12, g13;                             \
    READ_FA(0, 0)                                                              \
    READ_G0                                                                    \
    ISSUE_A_Q0(nb, ko)                                                         \
    MFMA_BLK0(0)                                                               \
    BAR                                                                        \
    READ_FA(0, 64)                                                             \
    READ_G1                                                                    \
    ISSUE_B_01(nb, ko)                                                         \
    MFMA_BLK1(0)                                                               \
    VMCNT(4);                                                                  \
    BAR                                                                        \
    READ_FA(8192, 0)                                                           \
    ISSUE_B_23(nb, ko)                                                         \
    MFMA_BLK0(4)                                                               \
    BAR                                                                        \
    READ_FA(8192, 64)                                                          \
    ISSUE_A_Q1(nb, ko)                                                         \
    MFMA_BLK1(4)                                                               \
    VMCNT(2);                                                                  \
    BAR                                                                        \
  }                                                                            \
  {                                                                            \
    const int cb = ((NT)-1) & 1;                                               \
    const char* Ac = (const char*)Al + cb * 32768 + mh * 16384;                \
    const char* Bc = (const char*)Bl + cb * 32768 + nq * 8192;                 \
    bf16x8 fa0, fa1, fa2, fa3;                                                 \
    bf16x8 g00, g01, g02, g03, g10, g11, g12, g13;                             \
    READ_FA(0, 0)                                                              \
    READ_G0                                                                    \
    MFMA_BLK0(0)                                                               \
    BAR                                                                        \
    READ_FA(0, 64)                                                             \
    READ_G1                                                                    \
    MFMA_BLK1(0)                                                               \
    VMCNT(0);                                                                  \
    BAR                                                                        \
    READ_FA(8192, 0)                                                           \
    MFMA_BLK0(4)                                                               \
    BAR                                                                        \
    READ_FA(8192, 64)                                                          \
    MFMA_BLK1(4)                                                               \
  }

#define GEOM_SETUP                                                             \
  const int tid = threadIdx.x;                                                 \
  const int wave = tid >> 6;                                                   \
  const int lane = tid & 63;                                                   \
  const int mh = wave >> 2;                                                    \
  const int nq = wave & 3;                                                     \
  const int wr = mh * 128;                                                     \
  const int wc = nq * 64;                                                      \
  const int lrow = lane & 15;                                                  \
  const int lslot = lane >> 4;                                                 \
  const int sxor = ((lslot ^ (lrow & 7)) << 4);                                \
  const int off0 = (0 * 16 + lrow) * 128 + sxor;                               \
  const int off1 = (1 * 16 + lrow) * 128 + sxor;                               \
  const int off2 = (2 * 16 + lrow) * 128 + sxor;                               \
  const int off3 = (3 * 16 + lrow) * 128 + sxor;                               \
  const int srow = tid >> 3;                                                   \
  const int slsl = ((tid & 7) ^ (srow & 7)) * 8;

// h[assign, :] = relu(x[btok[assign]] @ W1[e] + b1[e]);  N = HDIM, K = DDIM
__global__ void __launch_bounds__(512, 2) gemm1_kernel(
    const bf16_t* __restrict__ xb, const bf16_t* __restrict__ W1t,
    const float* __restrict__ b1, const int* __restrict__ btok,
    const int* __restrict__ offsets, const int* __restrict__ counts,
    const int* __restrict__ tmap, bf16_t* __restrict__ h) {
  const int job = xcd_swz((int)blockIdx.x, GRID1);
  const int tidx = job >> 4;
  const int nblk = job & 15;
  if (tidx >= tmap[2 * MAX_MT]) return;
  const int e = tmap[tidx];
  const int m0 = tmap[MAX_MT + tidx];
  const int cnt = counts[e];
  const int aoff = offsets[e];
  const int n0 = nblk * 256;

  __shared__ __align__(16) bf16_t Al[8 * 64 * 64];  // 64 KB (8 slots)
  __shared__ __align__(16) bf16_t Bl[8 * 64 * 64];  // 64 KB

  GEOM_SETUP

  // deposit sources (fixed over K): A quarters (mh,q), B quarters (nq)
  auto aSrc = [&](int rit) {
    int arow = m0 + rit;
    if (arow > cnt - 1) arow = cnt - 1;  // clamp (stores masked later)
    return xb + (size_t)btok[aoff + arow] * DDIM + slsl;
  };
  const bf16_t* aS00 = aSrc(0 + srow);
  const bf16_t* aS01 = aSrc(64 + srow);
  const bf16_t* aS10 = aSrc(128 + srow);
  const bf16_t* aS11 = aSrc(192 + srow);
  const bf16_t* bS0 = W1t + ((size_t)e * HDIM + n0 + 0 + srow) * DDIM + slsl;
  const bf16_t* bS1 = W1t + ((size_t)e * HDIM + n0 + 64 + srow) * DDIM + slsl;
  const bf16_t* bS2 = W1t + ((size_t)e * HDIM + n0 + 128 + srow) * DDIM + slsl;
  const bf16_t* bS3 = W1t + ((size_t)e * HDIM + n0 + 192 + srow) * DDIM + slsl;

  f32x4 acc[8][4];
#pragma unroll
  for (int mf = 0; mf < 8; ++mf)
#pragma unroll
    for (int nf = 0; nf < 4; ++nf) acc[mf][nf] = (f32x4){0.f, 0.f, 0.f, 0.f};

  KLOOP(16)  // K = 1024

  // epilogue: h = relu(acc + b1), bf16 (r6/r8-validated)
  const int rbase = (lane >> 4) * 4;
  const float* b1e = b1 + (size_t)e * HDIM + n0;
#pragma unroll
  for (int nf = 0; nf < 4; ++nf) {
    const int cl = wc + nf * 16 + lrow;
    const float bb = b1e[cl];
#pragma unroll
    for (int mf = 0; mf < 8; ++mf) {
#pragma unroll
      for (int r = 0; r < 4; ++r) {
        const int grow = wr + mf * 16 + rbase + r;
        if (m0 + grow < cnt)
          h[(size_t)(aoff + m0 + grow) * HDIM + (n0 + cl)] =
              (bf16_t)fmaxf(acc[mf][nf][r] + bb, 0.f);
      }
    }
  }
}

// gemm2: per-assignment partials (no atomics) or atomic fallback.
template <int NT, int KSP, bool ATOMIC>
__global__ void __launch_bounds__(512, 2) gemm2_kernel(
    const bf16_t* __restrict__ h, const bf16_t* __restrict__ W2t,
    const float* __restrict__ b2, const int* __restrict__ btok,
    const float* __restrict__ bprob, const int* __restrict__ offsets,
    const int* __restrict__ counts, const int* __restrict__ tmap,
    float* __restrict__ o0, float* __restrict__ o1,
    float* __restrict__ out) {
  const int nwg = 4 * KSP * MAX_MT;
  const int job = xcd_swz((int)blockIdx.x, nwg);
  const int tidx = job / (4 * KSP);
  const int rem = job % (4 * KSP);
  const int nblk = rem & 3;
  const int kch = rem >> 2;
  if (tidx >= tmap[2 * MAX_MT]) return;
  const int e = tmap[tidx];
  const int m0 = tmap[MAX_MT + tidx];
  const int cnt = counts[e];
  const int aoff = offsets[e];
  const int n0 = nblk * 256;
  const int kbase = kch * (HDIM / KSP);

  __shared__ __align__(16) bf16_t Al[8 * 64 * 64];
  __shared__ __align__(16) bf16_t Bl[8 * 64 * 64];

  GEOM_SETUP

  auto aSrc = [&](int rit) {
    int arow = m0 + rit;
    if (arow > cnt - 1) arow = cnt - 1;
    return h + (size_t)(aoff + arow) * HDIM + kbase + slsl;
  };
  const bf16_t* aS00 = aSrc(0 + srow);
  const bf16_t* aS01 = aSrc(64 + srow);
  const bf16_t* aS10 = aSrc(128 + srow);
  const bf16_t* aS11 = aSrc(192 + srow);
  const bf16_t* bS0 =
      W2t + ((size_t)e * DDIM + n0 + 0 + srow) * HDIM + kbase + slsl;
  const bf16_t* bS1 =
      W2t + ((size_t)e * DDIM + n0 + 64 + srow) * HDIM + kbase + slsl;
  const bf16_t* bS2 =
      W2t + ((size_t)e * DDIM + n0 + 128 + srow) * HDIM + kbase + slsl;
  const bf16_t* bS3 =
      W2t + ((size_t)e * DDIM + n0 + 192 + srow) * HDIM + kbase + slsl;

  f32x4 acc[8][4];
#pragma unroll
  for (int mf = 0; mf < 8; ++mf)
#pragma unroll
    for (int nf = 0; nf < 4; ++nf) acc[mf][nf] = (f32x4){0.f, 0.f, 0.f, 0.f};

  KLOOP(NT)

  // epilogue (r6-validated)
  const int rbase = (lane >> 4) * 4;
  const float* b2e = b2 + (size_t)e * DDIM + n0;
  float bb[4];
#pragma unroll
  for (int nf = 0; nf < 4; ++nf)
    bb[nf] = (kch == 0) ? b2e[wc + nf * 16 + lrow] : 0.f;

  if (ATOMIC) {
#pragma unroll
    for (int mf = 0; mf < 8; ++mf) {
#pragma unroll
      for (int r = 0; r < 4; ++r) {
        const int grow = wr + mf * 16 + rbase + r;
        if (m0 + grow < cnt) {
          const int assign = aoff + m0 + grow;
          const int tok = btok[assign];
          const float p = bprob[assign];
          float* orow = out + (size_t)tok * DDIM + n0;
#pragma unroll
          for (int nf = 0; nf < 4; ++nf) {
            const int cl = wc + nf * 16 + lrow;
            atomicAdd(&orow[cl], (acc[mf][nf][r] + bb[nf]) * p);
          }
        }
      }
    }
  } else {
    float* obase = (kch == 0) ? o0 : o1;
#pragma unroll
    for (int mf = 0; mf < 8; ++mf) {
#pragma unroll
      for (int r = 0; r < 4; ++r) {
        const int grow = wr + mf * 16 + rbase + r;
        if (m0 + grow < cnt) {
          const int assign = aoff + m0 + grow;
          float* orow = obase + (size_t)assign * DDIM + n0;
#pragma unroll
          for (int nf = 0; nf < 4; ++nf) {
            const int cl = wc + nf * 16 + lrow;
            orow[cl] = acc[mf][nf][r] + bb[nf];
          }
        }
      }
    }
  }
}

// ---------------- launch ----------------

extern "C" void kernel_launch(void* const* d_in, const int* in_sizes, int n_in,
                              void* d_out, int out_size, void* d_ws,
                              size_t ws_size, hipStream_t stream) {
  const float* x = (const float*)d_in[0];
  const float* Wr = (const float*)d_in[1];
  const float* br = (const float*)d_in[2];
  const float* W1 = (const float*)d_in[3];
  const float* b1 = (const float*)d_in[4];
  const float* W2 = (const float*)d_in[5];
  const float* b2 = (const float*)d_in[6];
  // d_in[7] = k (fixed 2, hardcoded)

  char* w = (char*)d_ws;
  auto alloc = [&](size_t bytes) -> char* {
    char* p = w;
    w += (bytes + 255) & ~(size_t)255;
    return p;
  };
  bf16_t* xb = (bf16_t*)alloc((size_t)NTOK * DDIM * 2);            // 16.8 MB
  bf16_t* W1t = (bf16_t*)alloc((size_t)NEXP * DDIM * HDIM * 2);    // 67.1 MB
  bf16_t* W2t = (bf16_t*)alloc((size_t)NEXP * DDIM * HDIM * 2);    // 67.1 MB
  bf16_t* hbuf = (bf16_t*)alloc((size_t)NASSIGN * HDIM * 2);       // 134 MB
  int* btok = (int*)alloc(NASSIGN * 4);
  float* bprob = (float*)alloc(NASSIGN * 4);
  int2* ids = (int2*)alloc(NTOK * 8);
  float2* prs = (float2*)alloc(NTOK * 8);
  int2* amap = (int2*)alloc(NTOK * 8);
  int* ctrl = (int*)alloc(64);     // counts[8] + cursor[8]
  int* offsets = (int*)alloc(64);  // 9 used
  int* tmap = (int*)alloc((2 * MAX_MT + 1) * 4);
  int* counts = ctrl;
  int* cursor = ctrl + 8;
  // o0: fresh region after everything; o1: overlays dead xb+W1t (67.1<83.9MB)
  const size_t osz = (size_t)NASSIGN * DDIM * 4;  // 67.1 MB
  float* o0 = (float*)alloc(osz);
  float* o1 = (float*)d_ws;  // valid only during/after gemm2 (xb,W1t dead)
  const size_t needed = (size_t)(w - (char*)d_ws);
  const bool pathA = ws_size >= needed;
  (void)in_sizes; (void)n_in;

  float* out = (float*)d_out;

  hipMemsetAsync(ctrl, 0, 64, stream);
  if (!pathA)
    hipMemsetAsync(d_out, 0, (size_t)out_size * 4, stream);  // atomics target

  transpose_cvt_kernel<<<dim3(HDIM / 32, DDIM / 64, NEXP), dim3(32, 8), 0,
                         stream>>>(W1, W1t, DDIM, HDIM);
  transpose_cvt_kernel<<<dim3(DDIM / 32, HDIM / 64, NEXP), dim3(32, 8), 0,
                         stream>>>(W2, W2t, HDIM, DDIM);
  router_kernel<<<NTOK, 256, 0, stream>>>(x, Wr, br, ids, prs, counts, xb);
  scan_aux_kernel<<<1, 256, 0, stream>>>(counts, offsets, tmap, ids, prs,
                                         out + (size_t)NTOK * DDIM);
  scatter_kernel<<<NTOK / 256, 256, 0, stream>>>(ids, prs, offsets, cursor,
                                                 btok, bprob, amap);
  gemm1_kernel<<<GRID1, 512, 0, stream>>>(xb, W1t, b1, btok, offsets, counts,
                                          tmap, hbuf);
  if (pathA) {
    gemm2_kernel<32, 2, false><<<GRID2A, 512, 0, stream>>>(
        hbuf, W2t, b2, btok, bprob, offsets, counts, tmap, o0, o1, out);
    combine_kernel<<<NTOK, 256, 0, stream>>>(o0, o1, amap, bprob, out);
  } else {
    gemm2_kernel<64, 1, true><<<GRID2B, 512, 0, stream>>>(
        hbuf, W2t, b2, btok, bprob, offsets, counts, tmap, o0, o1, out);
  }
}

// Round 12
// 839.107 us; speedup vs baseline: 1.0016x; 1.0016x over previous
//
#include <hip/hip_runtime.h>
#include <hip/hip_bf16.h>

// MoE: N=8192 tokens, D=1024, H=4096, E=8 experts, top-k=2.
// Grouped GEMMs: 256x256, BK=64, 8 waves (2M x 4N), quarter-slot LDS
// double buffer (128 KB), 4 phases/K-tile with COUNTED vmcnt (never 0 in
// steady loop; wait BEFORE barrier so all waves' deposits are proven).
// gemm2: atomic-free partials + combine.

#define NTOK 8192
#define DDIM 1024
#define HDIM 4096
#define NEXP 8
#define NASSIGN (NTOK * 2)
#define MAX_MT 72               // max ceil-sum of per-expert 256-row tiles (71)
#define GRID1 (16 * MAX_MT)     // 1152, divisible by 8
#define GRID2A (4 * 2 * MAX_MT) // 576  (K-split x2, no atomics)
#define GRID2B (4 * MAX_MT)     // 288  (atomic fallback)

typedef __bf16 bf16_t;
typedef __bf16 bf16x2 __attribute__((ext_vector_type(2)));
typedef __bf16 bf16x4 __attribute__((ext_vector_type(4)));
typedef __bf16 bf16x8 __attribute__((ext_vector_type(8)));
typedef float f32x4 __attribute__((ext_vector_type(4)));

#define GLOAD16(gptr, lptr)                                                    \
  __builtin_amdgcn_global_load_lds(                                            \
      (const __attribute__((address_space(1))) void*)(gptr),                   \
      (__attribute__((address_space(3))) void*)(lptr), 16, 0, 0)

#define VMCNT(n) asm volatile("s_waitcnt vmcnt(" #n ")" ::: "memory")
#define BAR                                                                    \
  __builtin_amdgcn_s_barrier();                                                \
  __builtin_amdgcn_sched_barrier(0);

#define MFMA16(a, b, c) __builtin_amdgcn_mfma_f32_16x16x32_bf16(a, b, c, 0, 0, 0)

// bijective XCD swizzle: launched id -> logical job; nwg % 8 == 0
__device__ __forceinline__ int xcd_swz(int orig, int nwg) {
  const int cpx = nwg >> 3;
  return (orig & 7) * cpx + (orig >> 3);
}

// ---------------- weight transpose: [E][R][C] f32 -> [E][C][R] bf16 --------
__global__ void __launch_bounds__(256) transpose_cvt_kernel(
    const float* __restrict__ in, bf16_t* __restrict__ out, int R, int C) {
  __shared__ float tile[64][33];
  const size_t mat = (size_t)R * C;
  const float* ip = in + (size_t)blockIdx.z * mat;
  bf16_t* op = out + (size_t)blockIdx.z * mat;
  const int c0 = blockIdx.x * 32, r0 = blockIdx.y * 64;
  const int tx = threadIdx.x, ty = threadIdx.y;  // (32, 8)
#pragma unroll
  for (int i = 0; i < 8; ++i) {
    const int r = ty + 8 * i;
    tile[r][tx] = ip[(size_t)(r0 + r) * C + (c0 + tx)];
  }
  __syncthreads();
#pragma unroll
  for (int j = 0; j < 4; ++j) {
    const int c = ty + 8 * j;
    bf16x2 v;
    v[0] = (bf16_t)tile[2 * tx][c];
    v[1] = (bf16_t)tile[2 * tx + 1][c];
    *(bf16x2*)(op + (size_t)(c0 + c) * R + r0 + 2 * tx) = v;
  }
}

// ---------------- router (fused x -> bf16; wave-shuffle reduce) ------------
__global__ void __launch_bounds__(256) router_kernel(
    const float* __restrict__ x, const float* __restrict__ Wr,
    const float* __restrict__ br, int2* __restrict__ ids,
    float2* __restrict__ prs, int* __restrict__ counts,
    bf16_t* __restrict__ xb) {
  const int n = blockIdx.x;
  const int t = threadIdx.x;
  const int wave = t >> 6, lane = t & 63;
  const float4 xv = ((const float4*)(x + (size_t)n * DDIM))[t];
  bf16x4 o;
  o[0] = (bf16_t)xv.x; o[1] = (bf16_t)xv.y;
  o[2] = (bf16_t)xv.z; o[3] = (bf16_t)xv.w;
  ((bf16x4*)(xb + (size_t)n * DDIM))[t] = o;

  float acc[NEXP];
#pragma unroll
  for (int e = 0; e < NEXP; ++e) acc[e] = 0.f;
  const float xq[4] = {xv.x, xv.y, xv.z, xv.w};
#pragma unroll
  for (int q = 0; q < 4; ++q) {
    const float* w = Wr + (size_t)(4 * t + q) * NEXP;
#pragma unroll
    for (int e = 0; e < NEXP; ++e) acc[e] += xq[q] * w[e];
  }
#pragma unroll
  for (int off = 32; off >= 1; off >>= 1)
#pragma unroll
    for (int e = 0; e < NEXP; ++e) acc[e] += __shfl_down(acc[e], off);
  __shared__ float red[4][NEXP];
  if (lane == 0)
#pragma unroll
    for (int e = 0; e < NEXP; ++e) red[wave][e] = acc[e];
  __syncthreads();
  if (t == 0) {
    float l[NEXP];
#pragma unroll
    for (int e = 0; e < NEXP; ++e)
      l[e] = ((red[0][e] + red[1][e]) + (red[2][e] + red[3][e])) + br[e];
    int i1 = 0; float v1 = l[0];
    for (int e = 1; e < NEXP; ++e)
      if (l[e] > v1) { v1 = l[e]; i1 = e; }
    int i2 = (i1 == 0) ? 1 : 0; float v2 = l[i2];
    for (int e = 0; e < NEXP; ++e)
      if (e != i1 && l[e] > v2) { v2 = l[e]; i2 = e; }
    float denom = 0.f;
    for (int e = 0; e < NEXP; ++e) denom += expf(l[e] - v1);
    ids[n] = make_int2(i1, i2);
    prs[n] = make_float2(1.f / denom, expf(v2 - v1) / denom);
    atomicAdd(&counts[i1], 1);
    atomicAdd(&counts[i2], 1);
  }
}

// scan (thread 0, 256-row tiles) + aux loss
__global__ void __launch_bounds__(256) scan_aux_kernel(
    const int* __restrict__ counts, int* __restrict__ offsets,
    int* __restrict__ tmap, const int2* __restrict__ ids,
    const float2* __restrict__ prs, float* __restrict__ aux_out) {
  const int t = threadIdx.x;
  if (t == 0) {
    int off = 0, nt = 0;
    for (int e = 0; e < NEXP; ++e) {
      offsets[e] = off;
      const int c = counts[e];
      for (int m0 = 0; m0 < c; m0 += 256) {
        tmap[nt] = e;
        tmap[MAX_MT + nt] = m0;
        ++nt;
      }
      off += c;
    }
    offsets[NEXP] = off;
    tmap[2 * MAX_MT] = nt;
  }
  float imp[NEXP];
#pragma unroll
  for (int e = 0; e < NEXP; ++e) imp[e] = 0.f;
  for (int n = t; n < NTOK; n += 256) {
    const int2 id = ids[n];
    const float2 pr = prs[n];
#pragma unroll
    for (int e = 0; e < NEXP; ++e)
      imp[e] += (id.x == e ? pr.x : 0.f) + (id.y == e ? pr.y : 0.f);
  }
  __shared__ float red[256][NEXP];
#pragma unroll
  for (int e = 0; e < NEXP; ++e) red[t][e] = imp[e];
  __syncthreads();
  for (int s = 128; s >= 1; s >>= 1) {
    if (t < s) {
#pragma unroll
      for (int e = 0; e < NEXP; ++e) red[t][e] += red[t + s][e];
    }
    __syncthreads();
  }
  if (t == 0) {
    float m = 0.f;
    for (int e = 0; e < NEXP; ++e) m += red[0][e];
    m *= (1.f / NEXP);
    float v = 0.f;
    for (int e = 0; e < NEXP; ++e) {
      const float d = red[0][e] - m;
      v += d * d;
    }
    v *= (1.f / (NEXP - 1));  // ddof=1
    aux_out[0] = v / (m * m + 1e-9f);
  }
}

// scatter: bucket tokens; also record token -> (assign1, assign2)
__global__ void __launch_bounds__(256) scatter_kernel(
    const int2* __restrict__ ids, const float2* __restrict__ prs,
    const int* __restrict__ offsets, int* __restrict__ cursor,
    int* __restrict__ btok, float* __restrict__ bprob,
    int2* __restrict__ amap) {
  const int n = blockIdx.x * 256 + threadIdx.x;
  if (n >= NTOK) return;
  const int2 id = ids[n];
  const float2 pr = prs[n];
  int p = atomicAdd(&cursor[id.x], 1);
  const int a1 = offsets[id.x] + p;
  btok[a1] = n;
  bprob[a1] = pr.x;
  p = atomicAdd(&cursor[id.y], 1);
  const int a2 = offsets[id.y] + p;
  btok[a2] = n;
  bprob[a2] = pr.y;
  amap[n] = make_int2(a1, a2);
}

// combine: out[n] = p1*(o0+o1)[a1] + p2*(o0+o1)[a2]  (bias already in o0)
__global__ void __launch_bounds__(256) combine_kernel(
    const float* __restrict__ o0, const float* __restrict__ o1,
    const int2* __restrict__ amap, const float* __restrict__ bprob,
    float* __restrict__ out) {
  const int n = blockIdx.x;
  const int d = threadIdx.x * 4;
  const int2 a = amap[n];
  const float p1 = bprob[a.x], p2 = bprob[a.y];
  const float4 u0 = *(const float4*)(o0 + (size_t)a.x * DDIM + d);
  const float4 u1 = *(const float4*)(o1 + (size_t)a.x * DDIM + d);
  const float4 v0 = *(const float4*)(o0 + (size_t)a.y * DDIM + d);
  const float4 v1 = *(const float4*)(o1 + (size_t)a.y * DDIM + d);
  float4 r;
  r.x = p1 * (u0.x + u1.x) + p2 * (v0.x + v1.x);
  r.y = p1 * (u0.y + u1.y) + p2 * (v0.y + v1.y);
  r.z = p1 * (u0.z + u1.z) + p2 * (v0.z + v1.z);
  r.w = p1 * (u0.w + u1.w) + p2 * (v0.w + v1.w);
  *(float4*)(out + (size_t)n * DDIM + d) = r;
}

// ---------------- GEMM core machinery ---------------------------------------
// LDS slots (8 KB each, holding 64 rows x 64 k bf16, XOR-8 swizzled):
//   A: slot(buf, mh, q) = buf*4 + mh*2 + q     (mh = M-half, q = row-quarter)
//   B: slot(buf, nq)    = buf*4 + nq           (nq = 64-col quarter)
// Deposit: thread tid writes its 16B at slot_base + tid*16 (gload_lds linear);
// source k-slot l = (tid&7) ^ ((tid>>3)&7)  (both-sides swizzle, rule #21).
// Read (lane): off_f = (f*16+lrow)*128 + ((lslot ^ (lrow&7))<<4); ks1 = ^64.

#define ISSUE_A_Q0(NB, KO)                                                     \
  GLOAD16(aS00 + (KO), (char*)Al + ((NB)*4 + 0) * 8192 + wave * 1024);         \
  GLOAD16(aS10 + (KO), (char*)Al + ((NB)*4 + 2) * 8192 + wave * 1024);
#define ISSUE_A_Q1(NB, KO)                                                     \
  GLOAD16(aS01 + (KO), (char*)Al + ((NB)*4 + 1) * 8192 + wave * 1024);         \
  GLOAD16(aS11 + (KO), (char*)Al + ((NB)*4 + 3) * 8192 + wave * 1024);
#define ISSUE_B_01(NB, KO)                                                     \
  GLOAD16(bS0 + (KO), (char*)Bl + ((NB)*4 + 0) * 8192 + wave * 1024);          \
  GLOAD16(bS1 + (KO), (char*)Bl + ((NB)*4 + 1) * 8192 + wave * 1024);
#define ISSUE_B_23(NB, KO)                                                     \
  GLOAD16(bS2 + (KO), (char*)Bl + ((NB)*4 + 2) * 8192 + wave * 1024);          \
  GLOAD16(bS3 + (KO), (char*)Bl + ((NB)*4 + 3) * 8192 + wave * 1024);

#define READ_FA(QOFF, KX)                                                      \
  fa0 = *(const bf16x8*)(Ac + (QOFF) + (off0 ^ (KX)));                         \
  fa1 = *(const bf16x8*)(Ac + (QOFF) + (off1 ^ (KX)));                         \
  fa2 = *(const bf16x8*)(Ac + (QOFF) + (off2 ^ (KX)));                         \
  fa3 = *(const bf16x8*)(Ac + (QOFF) + (off3 ^ (KX)));
#define READ_G0                                                                \
  g00 = *(const bf16x8*)(Bc + off0);                                           \
  g01 = *(const bf16x8*)(Bc + off1);                                           \
  g02 = *(const bf16x8*)(Bc + off2);                                           \
  g03 = *(const bf16x8*)(Bc + off3);
#define READ_G1                                                                \
  g10 = *(const bf16x8*)(Bc + (off0 ^ 64));                                    \
  g11 = *(const bf16x8*)(Bc + (off1 ^ 64));                                    \
  g12 = *(const bf16x8*)(Bc + (off2 ^ 64));                                    \
  g13 = *(const bf16x8*)(Bc + (off3 ^ 64));

#define MROW(M, A, G0, G1, G2, G3)                                             \
  acc[M][0] = MFMA16(A, G0, acc[M][0]);                                        \
  acc[M][1] = MFMA16(A, G1, acc[M][1]);                                        \
  acc[M][2] = MFMA16(A, G2, acc[M][2]);                                        \
  acc[M][3] = MFMA16(A, G3, acc[M][3]);
#define MFMA_BLK0(MB)                                                          \
  __builtin_amdgcn_s_setprio(1);                                               \
  MROW(MB + 0, fa0, g00, g01, g02, g03)                                        \
  MROW(MB + 1, fa1, g00, g01, g02, g03)                                        \
  MROW(MB + 2, fa2, g00, g01, g02, g03)                                        \
  MROW(MB + 3, fa3, g00, g01, g02, g03)                                        \
  __builtin_amdgcn_s_setprio(0);
#define MFMA_BLK1(MB)                                                          \
  __builtin_amdgcn_s_setprio(1);                                               \
  MROW(MB + 0, fa0, g10, g11, g12, g13)                                        \
  MROW(MB + 1, fa1, g10, g11, g12, g13)                                        \
  MROW(MB + 2, fa2, g10, g11, g12, g13)                                        \
  MROW(MB + 3, fa3, g10, g11, g12, g13)                                        \
  __builtin_amdgcn_s_setprio(0);

// K-loop: NT K-tiles of 64. Steady loop issues tile t+1 while computing t;
// counted waits: vmcnt(4) @ ph1-end (proves A(t,q1)), vmcnt(2) @ ph3-end
// (proves A(t+1,q0)+B(t+1)); never 0 until the peeled final tile.
#define KLOOP(NT)                                                              \
  ISSUE_A_Q0(0, 0) ISSUE_B_01(0, 0) ISSUE_B_23(0, 0) ISSUE_A_Q1(0, 0)          \
  VMCNT(2);                                                                    \
  BAR                                                                          \
  _Pragma("unroll 1") for (int t = 0; t < (NT)-1; ++t) {                       \
    const int cb = t & 1, nb = cb ^ 1;                                         \
    const int ko = (t + 1) * 64;                                               \
    const char* Ac = (const char*)Al + cb * 32768 + mh * 16384;                \
    const char* Bc = (const char*)Bl + cb * 32768 + nq * 8192;                 \
    bf16x8 fa0, fa1, fa2, fa3;                                                 \
    bf16x8 g00, g01, g02, g03, g10, g11, g12, g13;                             \
    READ_FA(0, 0)                                                              \
    READ_G0                                                                    \
    ISSUE_A_Q0(nb, ko)                                                         \
    MFMA_BLK0(0)                                                               \
    BAR                                                                        \
    READ_FA(0, 64)                                                             \
    READ_G1                                                                    \
    ISSUE_B_01(nb, ko)                                                         \
    MFMA_BLK1(0)                                                               \
    VMCNT(4);                                                                  \
    BAR                                                                        \
    READ_FA(8192, 0)                                                           \
    ISSUE_B_23(nb, ko)                                                         \
    MFMA_BLK0(4)                                                               \
    BAR                                                                        \
    READ_FA(8192, 64)                                                          \
    ISSUE_A_Q1(nb, ko)                                                         \
    MFMA_BLK1(4)                                                               \
    VMCNT(2);                                                                  \
    BAR                                                                        \
  }                                                                            \
  {                                                                            \
    const int cb = ((NT)-1) & 1;                                               \
    const char* Ac = (const char*)Al + cb * 32768 + mh * 16384;                \
    const char* Bc = (const char*)Bl + cb * 32768 + nq * 8192;                 \
    bf16x8 fa0, fa1, fa2, fa3;                                                 \
    bf16x8 g00, g01, g02, g03, g10, g11, g12, g13;                             \
    READ_FA(0, 0)                                                              \
    READ_G0                                                                    \
    MFMA_BLK0(0)                                                               \
    BAR                                                                        \
    READ_FA(0, 64)                                                             \
    READ_G1                                                                    \
    MFMA_BLK1(0)                                                               \
    VMCNT(0);                                                                  \
    BAR                                                                        \
    READ_FA(8192, 0)                                                           \
    MFMA_BLK0(4)                                                               \
    BAR                                                                        \
    READ_FA(8192, 64)                                                          \
    MFMA_BLK1(4)                                                               \
  }

#define GEOM_SETUP                                                             \
  const int tid = threadIdx.x;                                                 \
  const int wave = tid >> 6;                                                   \
  const int lane = tid & 63;                                                   \
  const int mh = wave >> 2;                                                    \
  const int nq = wave & 3;                                                     \
  const int wr = mh * 128;                                                     \
  const int wc = nq * 64;                                                      \
  const int lrow = lane & 15;                                                  \
  const int lslot = lane >> 4;                                                 \
  const int sxor = ((lslot ^ (lrow & 7)) << 4);                                \
  const int off0 = (0 * 16 + lrow) * 128 + sxor;                               \
  const int off1 = (1 * 16 + lrow) * 128 + sxor;                               \
  const int off2 = (2 * 16 + lrow) * 128 + sxor;                               \
  const int off3 = (3 * 16 + lrow) * 128 + sxor;                               \
  const int srow = tid >> 3;                                                   \
  const int slsl = ((tid & 7) ^ (srow & 7)) * 8;

// h[assign, :] = relu(x[btok[assign]] @ W1[e] + b1[e]);  N = HDIM, K = DDIM
__global__ void __launch_bounds__(512, 2) gemm1_kernel(
    const bf16_t* __restrict__ xb, const bf16_t* __restrict__ W1t,
    const float* __restrict__ b1, const int* __restrict__ btok,
    const int* __restrict__ offsets, const int* __restrict__ counts,
    const int* __restrict__ tmap, bf16_t* __restrict__ h) {
  const int job = xcd_swz((int)blockIdx.x, GRID1);
  const int tidx = job >> 4;
  const int nblk = job & 15;
  if (tidx >= tmap[2 * MAX_MT]) return;
  const int e = tmap[tidx];
  const int m0 = tmap[MAX_MT + tidx];
  const int cnt = counts[e];
  const int aoff = offsets[e];
  const int n0 = nblk * 256;

  __shared__ __align__(16) bf16_t Al[8 * 64 * 64];  // 64 KB (8 slots)
  __shared__ __align__(16) bf16_t Bl[8 * 64 * 64];  // 64 KB

  GEOM_SETUP

  // deposit sources (fixed over K): A quarters (mh,q), B quarters (nq)
  auto aSrc = [&](int rit) {
    int arow = m0 + rit;
    if (arow > cnt - 1) arow = cnt - 1;  // clamp (stores masked later)
    return xb + (size_t)btok[aoff + arow] * DDIM + slsl;
  };
  const bf16_t* aS00 = aSrc(0 + srow);
  const bf16_t* aS01 = aSrc(64 + srow);
  const bf16_t* aS10 = aSrc(128 + srow);
  const bf16_t* aS11 = aSrc(192 + srow);
  const bf16_t* bS0 = W1t + ((size_t)e * HDIM + n0 + 0 + srow) * DDIM + slsl;
  const bf16_t* bS1 = W1t + ((size_t)e * HDIM + n0 + 64 + srow) * DDIM + slsl;
  const bf16_t* bS2 = W1t + ((size_t)e * HDIM + n0 + 128 + srow) * DDIM + slsl;
  const bf16_t* bS3 = W1t + ((size_t)e * HDIM + n0 + 192 + srow) * DDIM + slsl;

  f32x4 acc[8][4];
#pragma unroll
  for (int mf = 0; mf < 8; ++mf)
#pragma unroll
    for (int nf = 0; nf < 4; ++nf) acc[mf][nf] = (f32x4){0.f, 0.f, 0.f, 0.f};

  KLOOP(16)  // K = 1024

  // epilogue: h = relu(acc + b1), bf16 (r6/r8-validated)
  const int rbase = (lane >> 4) * 4;
  const float* b1e = b1 + (size_t)e * HDIM + n0;
#pragma unroll
  for (int nf = 0; nf < 4; ++nf) {
    const int cl = wc + nf * 16 + lrow;
    const float bb = b1e[cl];
#pragma unroll
    for (int mf = 0; mf < 8; ++mf) {
#pragma unroll
      for (int r = 0; r < 4; ++r) {
        const int grow = wr + mf * 16 + rbase + r;
        if (m0 + grow < cnt)
          h[(size_t)(aoff + m0 + grow) * HDIM + (n0 + cl)] =
              (bf16_t)fmaxf(acc[mf][nf][r] + bb, 0.f);
      }
    }
  }
}

// gemm2: per-assignment partials (no atomics) or atomic fallback.
template <int NT, int KSP, bool ATOMIC>
__global__ void __launch_bounds__(512, 2) gemm2_kernel(
    const bf16_t* __restrict__ h, const bf16_t* __restrict__ W2t,
    const float* __restrict__ b2, const int* __restrict__ btok,
    const float* __restrict__ bprob, const int* __restrict__ offsets,
    const int* __restrict__ counts, const int* __restrict__ tmap,
    float* __restrict__ o0, float* __restrict__ o1,
    float* __restrict__ out) {
  const int nwg = 4 * KSP * MAX_MT;
  const int job = xcd_swz((int)blockIdx.x, nwg);
  const int tidx = job / (4 * KSP);
  const int rem = job % (4 * KSP);
  const int nblk = rem & 3;
  const int kch = rem >> 2;
  if (tidx >= tmap[2 * MAX_MT]) return;
  const int e = tmap[tidx];
  const int m0 = tmap[MAX_MT + tidx];
  const int cnt = counts[e];
  const int aoff = offsets[e];
  const int n0 = nblk * 256;
  const int kbase = kch * (HDIM / KSP);

  __shared__ __align__(16) bf16_t Al[8 * 64 * 64];
  __shared__ __align__(16) bf16_t Bl[8 * 64 * 64];

  GEOM_SETUP

  auto aSrc = [&](int rit) {
    int arow = m0 + rit;
    if (arow > cnt - 1) arow = cnt - 1;
    return h + (size_t)(aoff + arow) * HDIM + kbase + slsl;
  };
  const bf16_t* aS00 = aSrc(0 + srow);
  const bf16_t* aS01 = aSrc(64 + srow);
  const bf16_t* aS10 = aSrc(128 + srow);
  const bf16_t* aS11 = aSrc(192 + srow);
  const bf16_t* bS0 =
      W2t + ((size_t)e * DDIM + n0 + 0 + srow) * HDIM + kbase + slsl;
  const bf16_t* bS1 =
      W2t + ((size_t)e * DDIM + n0 + 64 + srow) * HDIM + kbase + slsl;
  const bf16_t* bS2 =
      W2t + ((size_t)e * DDIM + n0 + 128 + srow) * HDIM + kbase + slsl;
  const bf16_t* bS3 =
      W2t + ((size_t)e * DDIM + n0 + 192 + srow) * HDIM + kbase + slsl;

  f32x4 acc[8][4];
#pragma unroll
  for (int mf = 0; mf < 8; ++mf)
#pragma unroll
    for (int nf = 0; nf < 4; ++nf) acc[mf][nf] = (f32x4){0.f, 0.f, 0.f, 0.f};

  KLOOP(NT)

  // epilogue (r6-validated)
  const int rbase = (lane >> 4) * 4;
  const float* b2e = b2 + (size_t)e * DDIM + n0;
  float bb[4];
#pragma unroll
  for (int nf = 0; nf < 4; ++nf)
    bb[nf] = (kch == 0) ? b2e[wc + nf * 16 + lrow] : 0.f;

  if (ATOMIC) {
#pragma unroll
    for (int mf = 0; mf < 8; ++mf) {
#pragma unroll
      for (int r = 0; r < 4; ++r) {
        const int grow = wr + mf * 16 + rbase + r;
        if (m0 + grow < cnt) {
          const int assign = aoff + m0 + grow;
          const int tok = btok[assign];
          const float p = bprob[assign];
          float* orow = out + (size_t)tok * DDIM + n0;
#pragma unroll
          for (int nf = 0; nf < 4; ++nf) {
            const int cl = wc + nf * 16 + lrow;
            atomicAdd(&orow[cl], (acc[mf][nf][r] + bb[nf]) * p);
          }
        }
      }
    }
  } else {
    float* obase = (kch == 0) ? o0 : o1;
#pragma unroll
    for (int mf = 0; mf < 8; ++mf) {
#pragma unroll
      for (int r = 0; r < 4; ++r) {
        const int grow = wr + mf * 16 + rbase + r;
        if (m0 + grow < cnt) {
          const int assign = aoff + m0 + grow;
          float* orow = obase + (size_t)assign * DDIM + n0;
#pragma unroll
          for (int nf = 0; nf < 4; ++nf) {
            const int cl = wc + nf * 16 + lrow;
            orow[cl] = acc[mf][nf][r] + bb[nf];
          }
        }
      }
    }
  }
}

// ---------------- launch ----------------

extern "C" void kernel_launch(void* const* d_in, const int* in_sizes, int n_in,
                              void* d_out, int out_size, void* d_ws,
                              size_t ws_size, hipStream_t stream) {
  const float* x = (const float*)d_in[0];
  const float* Wr = (const float*)d_in[1];
  const float* br = (const float*)d_in[2];
  const float* W1 = (const float*)d_in[3];
  const float* b1 = (const float*)d_in[4];
  const float* W2 = (const float*)d_in[5];
  const float* b2 = (const float*)d_in[6];
  // d_in[7] = k (fixed 2, hardcoded)

  char* w = (char*)d_ws;
  auto alloc = [&](size_t bytes) -> char* {
    char* p = w;
    w += (bytes + 255) & ~(size_t)255;
    return p;
  };
  bf16_t* xb = (bf16_t*)alloc((size_t)NTOK * DDIM * 2);            // 16.8 MB
  bf16_t* W1t = (bf16_t*)alloc((size_t)NEXP * DDIM * HDIM * 2);    // 67.1 MB
  bf16_t* W2t = (bf16_t*)alloc((size_t)NEXP * DDIM * HDIM * 2);    // 67.1 MB
  bf16_t* hbuf = (bf16_t*)alloc((size_t)NASSIGN * HDIM * 2);       // 134 MB
  int* btok = (int*)alloc(NASSIGN * 4);
  float* bprob = (float*)alloc(NASSIGN * 4);
  int2* ids = (int2*)alloc(NTOK * 8);
  float2* prs = (float2*)alloc(NTOK * 8);
  int2* amap = (int2*)alloc(NTOK * 8);
  int* ctrl = (int*)alloc(64);     // counts[8] + cursor[8]
  int* offsets = (int*)alloc(64);  // 9 used
  int* tmap = (int*)alloc((2 * MAX_MT + 1) * 4);
  int* counts = ctrl;
  int* cursor = ctrl + 8;
  // o0: fresh region after everything; o1: overlays dead xb+W1t (67.1<83.9MB)
  const size_t osz = (size_t)NASSIGN * DDIM * 4;  // 67.1 MB
  float* o0 = (float*)alloc(osz);
  float* o1 = (float*)d_ws;  // valid only during/after gemm2 (xb,W1t dead)
  const size_t needed = (size_t)(w - (char*)d_ws);
  const bool pathA = ws_size >= needed;
  (void)in_sizes; (void)n_in;

  float* out = (float*)d_out;

  hipMemsetAsync(ctrl, 0, 64, stream);
  if (!pathA)
    hipMemsetAsync(d_out, 0, (size_t)out_size * 4, stream);  // atomics target

  transpose_cvt_kernel<<<dim3(HDIM / 32, DDIM / 64, NEXP), dim3(32, 8), 0,
                         stream>>>(W1, W1t, DDIM, HDIM);
  transpose_cvt_kernel<<<dim3(DDIM / 32, HDIM / 64, NEXP), dim3(32, 8), 0,
                         stream>>>(W2, W2t, HDIM, DDIM);
  router_kernel<<<NTOK, 256, 0, stream>>>(x, Wr, br, ids, prs, counts, xb);
  scan_aux_kernel<<<1, 256, 0, stream>>>(counts, offsets, tmap, ids, prs,
                                         out + (size_t)NTOK * DDIM);
  scatter_kernel<<<NTOK / 256, 256, 0, stream>>>(ids, prs, offsets, cursor,
                                                 btok, bprob, amap);
  gemm1_kernel<<<GRID1, 512, 0, stream>>>(xb, W1t, b1, btok, offsets, counts,
                                          tmap, hbuf);
  if (pathA) {
    gemm2_kernel<32, 2, false><<<GRID2A, 512, 0, stream>>>(
        hbuf, W2t, b2, btok, bprob, offsets, counts, tmap, o0, o1, out);
    combine_kernel<<<NTOK, 256, 0, stream>>>(o0, o1, amap, bprob, out);
  } else {
    gemm2_kernel<64, 1, true><<<GRID2B, 512, 0, stream>>>(
        hbuf, W2t, b2, btok, bprob, offsets, counts, tmap, o0, o1, out);
  }
}